// Round 11
// baseline (155.838 us; speedup 1.0000x reference)
//
#include <hip/hip_runtime.h>
#include <hip/hip_bf16.h>

typedef __hip_bfloat16 bf16;
typedef __attribute__((ext_vector_type(8))) short bf16x8;
typedef __attribute__((ext_vector_type(4))) float f32x4;

#define NB 4
#define NS 2048
#define ND 1024
#define NH 16
#define DH 64
#define KQK 64
#define KV 32

// 0.125 * log2(e): QK^T scores land directly in log2 domain for exp2f softmax
#define QSCALE 0.18033688011112042f

__device__ __forceinline__ unsigned int pk2(float a, float b) {
  unsigned short ua = __bfloat16_as_ushort(__float2bfloat16(a));
  unsigned short ub = __bfloat16_as_ushort(__float2bfloat16(b));
  return (unsigned int)ua | ((unsigned int)ub << 16);
}
__device__ __forceinline__ bf16x8 cvt8(float4 a, float4 b) {
  union { unsigned int u[4]; bf16x8 v; } r;
  r.u[0] = pk2(a.x, a.y); r.u[1] = pk2(a.z, a.w);
  r.u[2] = pk2(b.x, b.y); r.u[3] = pk2(b.z, b.w);
  return r.v;
}

// -------- Stage 1: h[b,s,n] = x[b,s,:] . Wrow[n]  (direct-fragment MFMA) ------
__global__ __launch_bounds__(256) void h_direct(
    const float* __restrict__ x,
    const int* __restrict__ idx_qk, const int* __restrict__ idx_v,
    const float* __restrict__ Fqk, const float* __restrict__ Fv,
    bf16* __restrict__ h_qk, bf16* __restrict__ h_v) {
  const int s0 = (blockIdx.x & 127) * 16;
  const int b  = blockIdx.x >> 7;
  const int tid = threadIdx.x, w = tid >> 6, l = tid & 63;
  const int lr = l & 15, lg = l >> 4;

  __shared__ float Red[4][16][100];

  const float* wrow[6];
#pragma unroll
  for (int nt = 0; nt < 6; ++nt) {
    int n = nt * 16 + lr;
    int idx = (n < KQK) ? idx_qk[b * KQK + n] : idx_v[b * KV + n - KQK];
    wrow[nt] = ((n < KQK) ? Fqk : Fv) + (size_t)idx * ND;
  }
  const float* xrow = x + ((size_t)b * NS + s0 + lr) * ND;

  f32x4 acc[6];
#pragma unroll
  for (int nt = 0; nt < 6; ++nt) acc[nt] = (f32x4)(0.f);

  const int kbase = w * 256;
  for (int kc = 0; kc < 8; ++kc) {
    const int k0 = kbase + kc * 32 + lg * 8;
    float4 xa = *(const float4*)(xrow + k0);
    float4 xb = *(const float4*)(xrow + k0 + 4);
    bf16x8 af = cvt8(xa, xb);
#pragma unroll
    for (int nt = 0; nt < 6; ++nt) {
      float4 wa = *(const float4*)(wrow[nt] + k0);
      float4 wb = *(const float4*)(wrow[nt] + k0 + 4);
      acc[nt] = __builtin_amdgcn_mfma_f32_16x16x32_bf16(af, cvt8(wa, wb), acc[nt], 0, 0, 0);
    }
  }

#pragma unroll
  for (int nt = 0; nt < 6; ++nt)
#pragma unroll
    for (int r = 0; r < 4; ++r)
      Red[w][lg * 4 + r][nt * 16 + lr] = acc[nt][r];
  __syncthreads();

  const int s = tid >> 4, nb0 = tid & 15;
#pragma unroll
  for (int j = 0; j < 6; ++j) {
    int n = nb0 + 16 * j;
    float v = Red[0][s][n] + Red[1][s][n] + Red[2][s][n] + Red[3][s][n];
    size_t row = (size_t)b * NS + s0 + s;
    if (n < KQK) h_qk[row * KQK + n] = __float2bfloat16(v);
    else         h_v[row * KV + n - KQK] = __float2bfloat16(v);
  }
}

// -------- W_O fp32 -> bf16 (once) --------------------------------------------
__global__ __launch_bounds__(256) void wcvt(const float* __restrict__ W,
                                            bf16* __restrict__ Wb) {
  int i = blockIdx.x * 256 + threadIdx.x;
  float4 t = reinterpret_cast<const float4*>(W)[i];
  reinterpret_cast<uint2*>(Wb)[i] = make_uint2(pk2(t.x, t.y), pk2(t.z, t.w));
}

// -------- Stage 2: fused Q/K/V expansion, bf16 MFMA ---------------------------
__global__ __launch_bounds__(256) void expand_mfma(
    const bf16* __restrict__ hqk, const bf16* __restrict__ hv,
    const float* __restrict__ RQ, const float* __restrict__ RK,
    const float* __restrict__ VN,
    const int* __restrict__ idx_q, const int* __restrict__ idx_k,
    const int* __restrict__ idx_v2,
    bf16* __restrict__ Qb, bf16* __restrict__ Kb, bf16* __restrict__ Vb) {
  const int s0 = blockIdx.x * 128, d0 = blockIdx.y * 128, b = blockIdx.z;
  const int tid = threadIdx.x, w = tid >> 6, l = tid & 63;
  const int lr = l & 15, lg = l >> 4;
  const int wm = w >> 1, wn = w & 1;

  __shared__ __align__(16) short Ah[128][72];
  __shared__ __align__(16) short Av[128][40];
  __shared__ __align__(16) short Wt[128][72];

  for (int i = tid; i < 1024; i += 256) {
    int r = i >> 3, c = i & 7;
    *(bf16x8*)&Ah[r][c * 8] = *(const bf16x8*)((const short*)hqk + ((size_t)b * NS + s0 + r) * KQK + c * 8);
  }
  for (int i = tid; i < 512; i += 256) {
    int r = i >> 2, c = i & 3;
    *(bf16x8*)&Av[r][c * 8] = *(const bf16x8*)((const short*)hv + ((size_t)b * NS + s0 + r) * KV + c * 8);
  }

  auto stageW = [&](const float* Wsrc, const int* idxv, int KR) {
    for (int i = tid; i < KR * 16; i += 256) {
      int r = i & (KR - 1), dc = i / KR;
      const float* src = Wsrc + (size_t)idxv[b * KR + r] * ND + d0 + dc * 8;
      float4 t0 = *(const float4*)src;
      float4 t1 = *(const float4*)(src + 4);
      Wt[dc * 8 + 0][r] = __bfloat16_as_ushort(__float2bfloat16(t0.x));
      Wt[dc * 8 + 1][r] = __bfloat16_as_ushort(__float2bfloat16(t0.y));
      Wt[dc * 8 + 2][r] = __bfloat16_as_ushort(__float2bfloat16(t0.z));
      Wt[dc * 8 + 3][r] = __bfloat16_as_ushort(__float2bfloat16(t0.w));
      Wt[dc * 8 + 4][r] = __bfloat16_as_ushort(__float2bfloat16(t1.x));
      Wt[dc * 8 + 5][r] = __bfloat16_as_ushort(__float2bfloat16(t1.y));
      Wt[dc * 8 + 6][r] = __bfloat16_as_ushort(__float2bfloat16(t1.z));
      Wt[dc * 8 + 7][r] = __bfloat16_as_ushort(__float2bfloat16(t1.w));
    }
  };

  auto computeQK = [&](float scale, bf16* outp) {
    f32x4 acc[4][4];
#pragma unroll
    for (int mt = 0; mt < 4; ++mt)
#pragma unroll
      for (int nt = 0; nt < 4; ++nt) acc[mt][nt] = (f32x4)(0.f);
#pragma unroll
    for (int c2 = 0; c2 < 2; ++c2) {
      bf16x8 af[4], bfv[4];
#pragma unroll
      for (int t = 0; t < 4; ++t) {
        af[t]  = *(const bf16x8*)&Ah[wm * 64 + t * 16 + lr][c2 * 32 + lg * 8];
        bfv[t] = *(const bf16x8*)&Wt[wn * 64 + t * 16 + lr][c2 * 32 + lg * 8];
      }
#pragma unroll
      for (int mt = 0; mt < 4; ++mt)
#pragma unroll
        for (int nt = 0; nt < 4; ++nt)
          acc[mt][nt] = __builtin_amdgcn_mfma_f32_16x16x32_bf16(af[mt], bfv[nt], acc[mt][nt], 0, 0, 0);
    }
#pragma unroll
    for (int mt = 0; mt < 4; ++mt)
#pragma unroll
      for (int rr = 0; rr < 4; ++rr) {
        size_t row = (size_t)b * NS + s0 + wm * 64 + mt * 16 + lg * 4 + rr;
        short* orow = (short*)outp + row * ND + d0 + wn * 64;
#pragma unroll
        for (int nt = 0; nt < 4; ++nt)
          orow[nt * 16 + lr] = __bfloat16_as_ushort(__float2bfloat16(acc[mt][nt][rr] * scale));
      }
  };

  stageW(RQ, idx_q, 64);
  __syncthreads();
  computeQK(QSCALE, Qb);
  __syncthreads();
  stageW(RK, idx_k, 64);
  __syncthreads();
  computeQK(1.0f, Kb);
  __syncthreads();
  stageW(VN, idx_v2, 32);
  __syncthreads();
  {
    f32x4 acc[4][4];
#pragma unroll
    for (int mt = 0; mt < 4; ++mt)
#pragma unroll
      for (int nt = 0; nt < 4; ++nt) acc[mt][nt] = (f32x4)(0.f);
    bf16x8 af[4], bfv[4];
#pragma unroll
    for (int t = 0; t < 4; ++t) {
      af[t]  = *(const bf16x8*)&Av[wm * 64 + t * 16 + lr][lg * 8];
      bfv[t] = *(const bf16x8*)&Wt[wn * 64 + t * 16 + lr][lg * 8];
    }
#pragma unroll
    for (int mt = 0; mt < 4; ++mt)
#pragma unroll
      for (int nt = 0; nt < 4; ++nt)
        acc[mt][nt] = __builtin_amdgcn_mfma_f32_16x16x32_bf16(af[mt], bfv[nt], acc[mt][nt], 0, 0, 0);
#pragma unroll
    for (int mt = 0; mt < 4; ++mt)
#pragma unroll
      for (int rr = 0; rr < 4; ++rr) {
        size_t row = (size_t)b * NS + s0 + wm * 64 + mt * 16 + lg * 4 + rr;
        short* orow = (short*)Vb + row * ND + d0 + wn * 64;
#pragma unroll
        for (int nt = 0; nt < 4; ++nt)
          orow[nt * 16 + lr] = __bfloat16_as_ushort(__float2bfloat16(acc[mt][nt][rr]));
      }
  }
}

// -------- Stage 3: causal flash attention, 8 waves x 16 q-rows, paired --------
// Swapped QK^T; log2-domain max-free softmax (p = exp2(s); inputs bounded so
// no overflow; masked entries use -1e30 -> exp2 = 0).
__global__ __launch_bounds__(512, 4) void attn_mfma(
    const bf16* __restrict__ Q, const bf16* __restrict__ K,
    const bf16* __restrict__ V, bf16* __restrict__ out) {
  const int wg = blockIdx.x;
  const int swz = (wg & 7) * 64 + (wg >> 3);     // XCD-contiguous
  const int pr = swz & 7, hh = (swz >> 3) & 15, b = swz >> 7;
  const int tid = threadIdx.x, wq = tid >> 6, l = tid & 63;
  const int lr = l & 15, lg = l >> 4;

  __shared__ __align__(16) short Ks[2][64][72];
  __shared__ __align__(16) short Vt[2][64][72];
  __shared__ __align__(16) short Ps[8][16][72];

  const short* Qp = (const short*)Q + (size_t)(b * NS) * ND + hh * DH;
  const short* Kp = (const short*)K + (size_t)(b * NS) * ND + hh * DH;
  const short* Vp = (const short*)V + (size_t)(b * NS) * ND + hh * DH;

  const int krow = tid >> 3, kcol = (tid & 7) * 8;
  const int vk = tid & 63, vd = (tid >> 6) * 8;
  bf16x8 kreg, vreg;

  auto LOAD = [&](int kt) {
    kreg = *(const bf16x8*)(Kp + (size_t)(kt * 64 + krow) * ND + kcol);
    vreg = *(const bf16x8*)(Vp + (size_t)(kt * 64 + vk) * ND + vd);
  };
  auto WRITE = [&](int buf) {
    *(bf16x8*)&Ks[buf][krow][kcol] = kreg;
#pragma unroll
    for (int j = 0; j < 8; ++j) Vt[buf][vd + j][vk] = vreg[j];
  };

  for (int pass = 0; pass < 2; ++pass) {
    const int qt = pass ? (15 - pr) : pr;
    const int q0 = qt * 128;

    bf16x8 qf[2];
    {
      const short* qrow = Qp + (size_t)(q0 + wq * 16 + lr) * ND;
      qf[0] = *(const bf16x8*)(qrow + lg * 8);
      qf[1] = *(const bf16x8*)(qrow + 32 + lg * 8);
    }
    f32x4 Oacc[4];
#pragma unroll
    for (int dt = 0; dt < 4; ++dt) Oacc[dt] = (f32x4)(0.f);
    float l_r = 0.f;

    const int NT = 2 * qt + 2;
    const int wlast = 2 * qt + (wq >> 2);   // wave-uniform diagonal k-tile

    LOAD(0);
    WRITE(0);
    __syncthreads();

    for (int kt = 0; kt < NT; ++kt) {
      const int cur = kt & 1;
      const bool more = (kt + 1 < NT);
      if (more) LOAD(kt + 1);

      if (kt <= wlast) {
        // S^T = K . Q^T  (cols = this wave's 16 q-rows)
        f32x4 s[4];
        __builtin_amdgcn_s_setprio(1);
#pragma unroll
        for (int t = 0; t < 4; ++t) {
          bf16x8 kf0 = *(const bf16x8*)&Ks[cur][t * 16 + lr][lg * 8];
          bf16x8 kf1 = *(const bf16x8*)&Ks[cur][t * 16 + lr][32 + lg * 8];
          f32x4 a = __builtin_amdgcn_mfma_f32_16x16x32_bf16(kf0, qf[0], (f32x4)(0.f), 0, 0, 0);
          s[t] = __builtin_amdgcn_mfma_f32_16x16x32_bf16(kf1, qf[1], a, 0, 0, 0);
        }
        __builtin_amdgcn_s_setprio(0);
        const bool diag = (kt == wlast);
        float p[4][4];
        if (diag) {
          const int qg = q0 + wq * 16 + lr;
#pragma unroll
          for (int t = 0; t < 4; ++t)
#pragma unroll
            for (int r = 0; r < 4; ++r) {
              float sv = s[t][r];
              if ((kt * 64 + t * 16 + lg * 4 + r) > qg) sv = -1e30f;
              float pv = exp2f(sv);
              p[t][r] = pv;
              l_r += pv;
            }
        } else {
#pragma unroll
          for (int t = 0; t < 4; ++t)
#pragma unroll
            for (int r = 0; r < 4; ++r) {
              float pv = exp2f(s[t][r]);
              p[t][r] = pv;
              l_r += pv;
            }
        }
        // P -> LDS (one b64 store per t: hits the 4-dword/bank floor)
#pragma unroll
        for (int t = 0; t < 4; ++t)
          *(uint2*)&Ps[wq][lr][t * 16 + lg * 4] =
              make_uint2(pk2(p[t][0], p[t][1]), pk2(p[t][2], p[t][3]));
        bf16x8 pa0 = *(const bf16x8*)&Ps[wq][lr][lg * 8];
        bf16x8 pa1 = *(const bf16x8*)&Ps[wq][lr][32 + lg * 8];
        __builtin_amdgcn_s_setprio(1);
#pragma unroll
        for (int dt = 0; dt < 4; ++dt) {
          bf16x8 vf0 = *(const bf16x8*)&Vt[cur][dt * 16 + lr][lg * 8];
          bf16x8 vf1 = *(const bf16x8*)&Vt[cur][dt * 16 + lr][32 + lg * 8];
          Oacc[dt] = __builtin_amdgcn_mfma_f32_16x16x32_bf16(pa0, vf0, Oacc[dt], 0, 0, 0);
          Oacc[dt] = __builtin_amdgcn_mfma_f32_16x16x32_bf16(pa1, vf1, Oacc[dt], 0, 0, 0);
        }
        __builtin_amdgcn_s_setprio(0);
      }
      if (more) WRITE((kt + 1) & 1);
      __syncthreads();
    }

    // epilogue (registers only)
    float lf = l_r;
    lf += __shfl_xor(lf, 16, 64);
    lf += __shfl_xor(lf, 32, 64);
    const float linv = 1.f / lf;
#pragma unroll
    for (int r = 0; r < 4; ++r) {
      float lb = __shfl(linv, (l & 48) | (lg * 4 + r), 64);
      size_t row = (size_t)(b * NS) + q0 + wq * 16 + lg * 4 + r;
      short* orow = (short*)out + row * ND + hh * DH;
#pragma unroll
      for (int dt = 0; dt < 4; ++dt)
        orow[dt * 16 + lr] = __bfloat16_as_ushort(__float2bfloat16(Oacc[dt][r] * lb));
    }
  }
}

// -------- Stage 4: C[m,i] = sum_j A[m,j] * Wb[i,j]  (bf16 MFMA, BK=64) --------
__global__ __launch_bounds__(256) void out_gemm_mfma(
    const bf16* __restrict__ A, const bf16* __restrict__ W,
    float* __restrict__ C) {
  const int m0 = blockIdx.x * 128, i0 = blockIdx.y * 128;
  const int tid = threadIdx.x, w = tid >> 6, l = tid & 63;
  const int lr = l & 15, lg = l >> 4;
  const int wm = w >> 1, wn = w & 1;

  __shared__ __align__(16) short As[128][72];
  __shared__ __align__(16) short Bs[128][72];

  f32x4 acc[4][4];
#pragma unroll
  for (int a = 0; a < 4; ++a)
#pragma unroll
    for (int bb = 0; bb < 4; ++bb) acc[a][bb] = (f32x4)(0.f);

  for (int j0 = 0; j0 < ND; j0 += 64) {
    __syncthreads();
    for (int v = tid; v < 1024; v += 256) {
      int r = v >> 3, c = v & 7;
      *(bf16x8*)&As[r][c * 8] = *(const bf16x8*)((const short*)A + ((size_t)m0 + r) * ND + j0 + c * 8);
      *(bf16x8*)&Bs[r][c * 8] = *(const bf16x8*)((const short*)W + ((size_t)i0 + r) * ND + j0 + c * 8);
    }
    __syncthreads();
#pragma unroll
    for (int c2 = 0; c2 < 2; ++c2) {
      bf16x8 af[4], bfv[4];
#pragma unroll
      for (int t = 0; t < 4; ++t) {
        af[t]  = *(const bf16x8*)&As[wm * 64 + t * 16 + lr][c2 * 32 + lg * 8];
        bfv[t] = *(const bf16x8*)&Bs[wn * 64 + t * 16 + lr][c2 * 32 + lg * 8];
      }
#pragma unroll
      for (int mt = 0; mt < 4; ++mt)
#pragma unroll
        for (int nt = 0; nt < 4; ++nt)
          acc[mt][nt] = __builtin_amdgcn_mfma_f32_16x16x32_bf16(af[mt], bfv[nt], acc[mt][nt], 0, 0, 0);
    }
  }
#pragma unroll
  for (int mt = 0; mt < 4; ++mt)
#pragma unroll
    for (int r = 0; r < 4; ++r) {
      size_t row = (size_t)m0 + wm * 64 + mt * 16 + lg * 4 + r;
#pragma unroll
      for (int nt = 0; nt < 4; ++nt)
        C[row * ND + i0 + wn * 64 + nt * 16 + lr] = acc[mt][nt][r];
    }
}

extern "C" void kernel_launch(void* const* d_in, const int* in_sizes, int n_in,
                              void* d_out, int out_size, void* d_ws, size_t ws_size,
                              hipStream_t stream) {
  const float* x      = (const float*)d_in[0];
  const int* idx_qk   = (const int*)d_in[1];
  const int* idx_v    = (const int*)d_in[2];
  const int* idx_q    = (const int*)d_in[3];
  const int* idx_k    = (const int*)d_in[4];
  const int* idx_v2   = (const int*)d_in[5];
  const float* Fqk    = (const float*)d_in[6];
  const float* Fv     = (const float*)d_in[7];
  const float* RQ     = (const float*)d_in[8];
  const float* RK     = (const float*)d_in[9];
  const float* VN     = (const float*)d_in[10];
  const float* W_O    = (const float*)d_in[11];

  bf16* h_qk = (bf16*)d_ws;                            // 4*2048*64 bf16
  bf16* h_v  = h_qk + (size_t)NB * NS * KQK;           // 4*2048*32 bf16
  bf16* Qb   = h_v + (size_t)NB * NS * KV;
  bf16* Kb   = Qb + (size_t)NB * NS * ND;
  bf16* Vb   = Kb + (size_t)NB * NS * ND;
  bf16* Ob   = Vb + (size_t)NB * NS * ND;              // attention output bf16
  bf16* Wb   = Ob + (size_t)NB * NS * ND;              // W_O bf16

  h_direct<<<dim3(NB * NS / 16), 256, 0, stream>>>(x, idx_qk, idx_v, Fqk, Fv, h_qk, h_v);
  wcvt<<<ND * ND / 4 / 256, 256, 0, stream>>>(W_O, Wb);

  expand_mfma<<<dim3(NS / 128, ND / 128, NB), 256, 0, stream>>>(
      h_qk, h_v, RQ, RK, VN, idx_q, idx_k, idx_v2, Qb, Kb, Vb);

  attn_mfma<<<dim3(8 * NH * NB), 512, 0, stream>>>(Qb, Kb, Vb, Ob);

  out_gemm_mfma<<<dim3(NB * NS / 128, ND / 128), 256, 0, stream>>>(Ob, Wb, (float*)d_out);
}